// Round 1
// 498.037 us; speedup vs baseline: 1.0083x; 1.0083x over previous
//
#include <hip/hip_runtime.h>
#include <stdint.h>

#define NND 200000   // N nodes; D_IN = D_OUT = 256, B = 256

typedef unsigned short u16;
typedef __attribute__((ext_vector_type(4))) float f4;
typedef __attribute__((ext_vector_type(4))) int   i4;
typedef __attribute__((ext_vector_type(2))) unsigned int u2;
typedef __attribute__((ext_vector_type(8))) short s8;   // 8 bf16 - MFMA A/B frag
typedef __attribute__((ext_vector_type(4))) float acc4; // MFMA C/D frag

__device__ __forceinline__ short f2bf(float f) {
    union { float f; uint32_t u; } v; v.f = f;
    uint32_t r = v.u + 0x7FFFu + ((v.u >> 16) & 1u);   // RNE
    return (short)(r >> 16);
}
__device__ __forceinline__ uint32_t pack2bf(float a, float b) {
    uint32_t ua = __float_as_uint(a), ub = __float_as_uint(b);
    ua = ua + 0x7FFFu + ((ua >> 16) & 1u);
    ub = ub + 0x7FFFu + ((ub >> 16) & 1u);
    return (ua >> 16) | (ub & 0xFFFF0000u);
}
__device__ __forceinline__ void gld16(const void* g, void* l) {
    __builtin_amdgcn_global_load_lds(
        (const __attribute__((address_space(1))) void*)g,
        (__attribute__((address_space(3))) void*)l, 16, 0, 0);
}

// ---------------- prep: W fp32 -> bf16 ----------------
__global__ __launch_bounds__(256) void k_prep(const float* __restrict__ Wt,
                                              const float* __restrict__ Wg,
                                              u16* __restrict__ wtb,
                                              u16* __restrict__ wgb) {
    int i = blockIdx.x * 256 + threadIdx.x;   // 256 blocks -> 65536 exactly
    wtb[i] = (u16)f2bf(Wt[i]);
    wgb[i] = (u16)f2bf(Wg[i]);
}

// ---------------- pass 1: h_t[d][n] = (nodes@Wt.T+bt)*sigmoid(nodes@Wg.T+bg) ----------------
// W-RESIDENT STREAMING VERSION.
// 250 blocks x 1024 threads (16 waves), 1 block/CU. Wave w owns d-slice w*16..w*16+15.
// Both W matrices live in per-wave REGISTERS (8 ks x 2 mats x s8 = 64 VGPR/lane) -> no W
// staging in the loop at all. Nodes streamed in 32-row chunks through double-buffered
// LDS (frag-ordered, xor-swizzled), ONE barrier per chunk, global loads issued a full
// phase ahead. 250 x 25 x 32 = 200000 exactly -> no tail, no bounds checks.
__global__ __launch_bounds__(1024, 4) void k_h(const float* __restrict__ nodes,
                                               const u16* __restrict__ wtb,
                                               const u16* __restrict__ wgb,
                                               const float* __restrict__ btp,
                                               const float* __restrict__ bgp,
                                               u16* __restrict__ h_t) {
    // A dbuf: 2 x 16384 (32 rows x 256 k bf16, frag-ordered granules)
    // H dbuf: 2 x 18432 (256 d x 72B rows: 64B data + 8B pad -> conflict-free transpose)
    __shared__ __align__(16) char smem[69632];
    char* A0 = smem;
    char* A1 = smem + 16384;
    char* H0 = smem + 32768;
    char* H1 = smem + 51200;

    const int tid  = threadIdx.x;
    const int lane = tid & 63, wave = tid >> 6;
    const int quad = lane >> 4, l16 = lane & 15;
    const int dgl  = wave * 16 + l16;          // this lane's output-d (B-frag col)

    // ---- W fragments -> registers (once; wtb/wgb are L2/L3-hot, 128KB total) ----
    s8 wT[8], wG[8];
    {
        const u16* wtp = wtb + dgl * 256 + quad * 8;
        const u16* wgp = wgb + dgl * 256 + quad * 8;
#pragma unroll
        for (int ks = 0; ks < 8; ++ks) {
            wT[ks] = *(const s8*)(wtp + ks * 32);
            wG[ks] = *(const s8*)(wgp + ks * 32);
        }
    }
    const float btv = btp[dgl], bgv = bgp[dgl];

    const int c0   = blockIdx.x * 25;          // first 32-node chunk of this block
    const int arow = tid >> 5, akq = tid & 31; // A load: 32 thr/row -> contiguous 1KB/row
    const int awbyte = akq * 512 + (((arow & 24) | ((arow ^ akq) & 7)) << 4); // swizzled granule
    const int sd = tid >> 2, sc = tid & 3;     // H store: 4 thr/d-row, 16B each

    // ---- prologue: chunk c0 -> A0; prefetch chunk c0+1 into regs ----
    f4 ar0, ar1;
    {
        const f4* p = (const f4*)(nodes + (size_t)(c0 * 32 + arow) * 256 + akq * 8);
        ar0 = p[0]; ar1 = p[1];
        i4 aw;
        aw.x = (int)pack2bf(ar0.x, ar0.y); aw.y = (int)pack2bf(ar0.z, ar0.w);
        aw.z = (int)pack2bf(ar1.x, ar1.y); aw.w = (int)pack2bf(ar1.z, ar1.w);
        *(i4*)(A0 + awbyte) = aw;
        const f4* q = (const f4*)(nodes + (size_t)((c0 + 1) * 32 + arow) * 256 + akq * 8);
        ar0 = q[0]; ar1 = q[1];
    }
    __syncthreads();

    char *Ard = A0, *Awr = A1, *Hwr = H0, *Hrd = H1;

    for (int c = 0; c < 25; ++c) {
        // ---- MFMA: 32 rows x 16 d x K=256, both matrices (32 MFMA/wave) ----
        acc4 at0 = (acc4)0.0f, at1 = (acc4)0.0f, ag0 = (acc4)0.0f, ag1 = (acc4)0.0f;
#pragma unroll
        for (int ks = 0; ks < 8; ++ks) {
            const int kq = ks * 4 + quad;
            const int ab = kq * 512 + (((l16 & 8) | ((l16 ^ kq) & 7)) << 4);
            s8 af0 = *(const s8*)(Ard + ab);         // rows  0..15
            s8 af1 = *(const s8*)(Ard + ab + 256);   // rows 16..31 (same swizzle slot +256B)
            at0 = __builtin_amdgcn_mfma_f32_16x16x32_bf16(af0, wT[ks], at0, 0, 0, 0);
            ag0 = __builtin_amdgcn_mfma_f32_16x16x32_bf16(af0, wG[ks], ag0, 0, 0, 0);
            at1 = __builtin_amdgcn_mfma_f32_16x16x32_bf16(af1, wT[ks], at1, 0, 0, 0);
            ag1 = __builtin_amdgcn_mfma_f32_16x16x32_bf16(af1, wG[ks], ag1, 0, 0, 0);
        }
        // ---- stage chunk c+1 (already in regs) into the other A buffer ----
        if (c < 24) {
            i4 aw;
            aw.x = (int)pack2bf(ar0.x, ar0.y); aw.y = (int)pack2bf(ar0.z, ar0.w);
            aw.z = (int)pack2bf(ar1.x, ar1.y); aw.w = (int)pack2bf(ar1.z, ar1.w);
            *(i4*)(Awr + awbyte) = aw;
        }
        // ---- issue global loads for chunk c+2 (complete during next phase) ----
        if (c < 23) {
            const f4* p = (const f4*)(nodes + (size_t)((c0 + c + 2) * 32 + arow) * 256 + akq * 8);
            ar0 = p[0]; ar1 = p[1];
        }
        // ---- epilogue: h = (data+bt)*sigmoid(gate+bg) -> bf16 -> Hwr (transpose tile) ----
#pragma unroll
        for (int rt = 0; rt < 2; ++rt) {
            const acc4 t = rt ? at1 : at0;
            const acc4 g = rt ? ag1 : ag0;
            float h0 = (t[0] + btv) / (1.0f + __expf(-(g[0] + bgv)));
            float h1 = (t[1] + btv) / (1.0f + __expf(-(g[1] + bgv)));
            float h2 = (t[2] + btv) / (1.0f + __expf(-(g[2] + bgv)));
            float h3 = (t[3] + btv) / (1.0f + __expf(-(g[3] + bgv)));
            u2 p; p.x = pack2bf(h0, h1); p.y = pack2bf(h2, h3);
            *(u2*)(Hwr + dgl * 72 + rt * 32 + quad * 8) = p;
        }
        // ---- coalesced store of PREVIOUS chunk's h tile (other H buffer) ----
        if (c > 0) {
            f4 v = *(const f4*)(Hrd + sd * 72 + sc * 16);
            *(f4*)(h_t + (size_t)sd * NND + (size_t)(c0 + c - 1) * 32 + sc * 8) = v;
        }
        __syncthreads();
        char* tp = Ard; Ard = Awr; Awr = tp;
        tp = Hwr; Hwr = Hrd; Hrd = tp;
    }
    // ---- final store: chunk c0+24 ----
    {
        f4 v = *(const f4*)(Hrd + sd * 72 + sc * 16);
        *(f4*)(h_t + (size_t)sd * NND + (size_t)(c0 + 24) * 32 + sc * 8) = v;
    }
}

// ---------------- pass 2: res = mask @ h_t^T, split-K ----------------
// 512 threads = 8 waves. Block: 128 b x 256 d; wave (bh,dq) = 64b x 64d (acc 64 VGPR).
// grid (2, 209): 418 blocks, 15 rounds x 64 n (last split 5). Mask regs prefetched across barrier.
__global__ __launch_bounds__(512, 4) void k_res(const int* __restrict__ masks,
                                                const u16* __restrict__ h_t,
                                                float* __restrict__ outp) {
    __shared__ __align__(16) char smem[49152];
    u16* Ms = (u16*)smem;             // 128 b x 128B bf16, slot-swizzled (reg-written)
    u16* Hs = (u16*)(smem + 16384);   // 256 d x 128B bf16, slot-swizzled (gld16 dest)

    const int tid  = threadIdx.x;
    const int lane = tid & 63, wave = tid >> 6;
    const int quad = lane >> 4, l16 = lane & 15;
    const int bh = wave & 1, dq = wave >> 1;
    const int b0 = blockIdx.x * 128;
    const int nbase = blockIdx.y * 960;
    const int R = min(15, (NND - nbase) / 64);

    acc4 acc[4][4];
#pragma unroll
    for (int rt = 0; rt < 4; ++rt)
#pragma unroll
        for (int dt = 0; dt < 4; ++dt) acc[rt][dt] = (acc4)0.0f;

    const int mr0 = tid >> 3, mc0 = tid & 7;          // i=0 granule
    const int mr1 = (512 + tid) >> 3, mc1 = tid & 7;  // i=1 granule
    i4 mp[2][2];
    {   // prefetch masks for it=0
        const i4* p0 = (const i4*)(masks + (size_t)(b0 + mr0) * NND + nbase + mc0 * 8);
        const i4* p1 = (const i4*)(masks + (size_t)(b0 + mr1) * NND + nbase + mc1 * 8);
        mp[0][0] = p0[0]; mp[0][1] = p0[1];
        mp[1][0] = p1[0]; mp[1][1] = p1[1];
    }

    for (int it = 0; it < R; ++it) {
        const int nb = nbase + it * 64;
        // H: 256x64 bf16 via gld16 (L3-hot from pass 1), 4/thread
#pragma unroll
        for (int i = 0; i < 4; ++i) {
            int g = i * 512 + tid;
            int dr = g >> 3, c = g & 7;
            gld16(h_t + (size_t)dr * NND + nb + ((c ^ (dr & 7)) << 3), (char*)Hs + g * 16);
        }
        // convert prefetched mask regs -> bf16 LDS (b128 each)
#pragma unroll
        for (int i = 0; i < 2; ++i) {
            int mr = (i == 0) ? mr0 : mr1, c = (i == 0) ? mc0 : mc1;
            i4 w;
            w.x = (int)((((uint32_t)(-mp[i][0].x)) & 0x3F80u) | ((((uint32_t)(-mp[i][0].y)) & 0x3F80u) << 16));
            w.y = (int)((((uint32_t)(-mp[i][0].z)) & 0x3F80u) | ((((uint32_t)(-mp[i][0].w)) & 0x3F80u) << 16));
            w.z = (int)((((uint32_t)(-mp[i][1].x)) & 0x3F80u) | ((((uint32_t)(-mp[i][1].y)) & 0x3F80u) << 16));
            w.w = (int)((((uint32_t)(-mp[i][1].z)) & 0x3F80u) | ((((uint32_t)(-mp[i][1].w)) & 0x3F80u) << 16));
            *(i4*)((char*)Ms + mr * 128 + ((c ^ (mr & 7)) << 4)) = w;
        }
        __syncthreads();
        // prefetch next round's masks NOW -> in flight during MFMA
        if (it + 1 < R) {
            const int nn = nb + 64;
            const i4* p0 = (const i4*)(masks + (size_t)(b0 + mr0) * NND + nn + mc0 * 8);
            const i4* p1 = (const i4*)(masks + (size_t)(b0 + mr1) * NND + nn + mc1 * 8);
            mp[0][0] = p0[0]; mp[0][1] = p0[1];
            mp[1][0] = p1[0]; mp[1][1] = p1[1];
        }
#pragma unroll
        for (int ks = 0; ks < 2; ++ks) {
            const int q = (ks << 2) | quad;
            s8 af[4];
#pragma unroll
            for (int rt = 0; rt < 4; ++rt) {
                int r = bh * 64 + rt * 16 + l16;
                af[rt] = *(const s8*)((char*)Ms + r * 128 + ((q ^ (l16 & 7)) << 4));
            }
#pragma unroll
            for (int dt = 0; dt < 4; ++dt) {
                int dl = dq * 64 + dt * 16 + l16;
                s8 bf_ = *(const s8*)((char*)Hs + dl * 128 + ((q ^ (dl & 7)) << 4));
#pragma unroll
                for (int rt = 0; rt < 4; ++rt)
                    acc[rt][dt] = __builtin_amdgcn_mfma_f32_16x16x32_bf16(af[rt], bf_, acc[rt][dt], 0, 0, 0);
            }
        }
        __syncthreads();
    }
#pragma unroll
    for (int rt = 0; rt < 4; ++rt)
#pragma unroll
        for (int dt = 0; dt < 4; ++dt) {
            int b = b0 + bh * 64 + rt * 16 + quad * 4;
            int d = dq * 64 + dt * 16 + l16;
#pragma unroll
            for (int r = 0; r < 4; ++r)
                atomicAdd(outp + (size_t)(b + r) * 256 + d, acc[rt][dt][r]);
        }
}

extern "C" void kernel_launch(void* const* d_in, const int* in_sizes, int n_in,
                              void* d_out, int out_size, void* d_ws, size_t ws_size,
                              hipStream_t stream) {
    const float* nodes = (const float*)d_in[0];
    const int*   masks = (const int*)d_in[1];
    const float* Wt    = (const float*)d_in[2];
    const float* bt    = (const float*)d_in[3];
    const float* Wg    = (const float*)d_in[4];
    const float* bg    = (const float*)d_in[5];
    float* outp = (float*)d_out;

    // ws layout: h_t bf16 [256][200000] = 102,400,000 B; then Wt/Wg bf16 (131072 B)
    u16* h_t = (u16*)d_ws;
    u16* wtb = (u16*)((char*)d_ws + (size_t)102400000);
    u16* wgb = wtb + 65536;

    hipMemsetAsync(d_out, 0, (size_t)out_size * sizeof(float), stream);
    k_prep<<<dim3(256), dim3(256), 0, stream>>>(Wt, Wg, wtb, wgb);
    k_h<<<dim3(250), dim3(1024), 0, stream>>>(nodes, wtb, wgb, bt, bg, h_t);
    k_res<<<dim3(2, 209), dim3(512), 0, stream>>>(masks, h_t, outp);
}